// Round 8
// baseline (1073.552 us; speedup 1.0000x reference)
//
#include <hip/hip_runtime.h>

#define T_STEPS 512
#define HID     128

typedef _Float16 v8hf __attribute__((ext_vector_type(8)));
typedef float v4f __attribute__((ext_vector_type(4)));

__device__ __forceinline__ float rcpf(float x) {
#if __has_builtin(__builtin_amdgcn_rcpf)
  return __builtin_amdgcn_rcpf(x);
#else
  return 1.0f / x;
#endif
}
__device__ __forceinline__ float sigm(float x)  { return rcpf(1.0f + __expf(-x)); }
__device__ __forceinline__ float tanh_f(float x){ return 1.0f - 2.0f * rcpf(__expf(2.0f * x) + 1.0f); }

// ---------------------------------------------------------------- prep ----
// Gate-interleaved rows: packed row r = 4*u + g  <->  orig row g*128 + u.
// MFMA C row (rt*16 + q*4 + reg) then holds gate 'reg' of hidden u = rt*4+q.
__global__ __launch_bounds__(256) void prep_w(
    const float* __restrict__ Wih0, const float* __restrict__ Whh0,
    const float* __restrict__ bih0, const float* __restrict__ bhh0,
    const float* __restrict__ Wih1, const float* __restrict__ Whh1,
    const float* __restrict__ bih1, const float* __restrict__ bhh1,
    _Float16* __restrict__ Wcat0, _Float16* __restrict__ Wcat1,
    float* __restrict__ bias0, float* __restrict__ bias1) {
  int i = blockIdx.x * blockDim.x + threadIdx.x;
  if (i < 512 * 192) {                  // Wcat0 row r: [Wih0(64) | Whh0(128)]
    int r = i / 192, k = i - r * 192;
    int orig = (r & 3) * 128 + (r >> 2);
    float v = (k < 64) ? Wih0[orig * 64 + k] : Whh0[orig * 128 + (k - 64)];
    Wcat0[i] = (_Float16)v;
  }
  if (i < 512 * 256) {                  // Wcat1 row r: [Wih1(128) | Whh1(128)]
    int r = i >> 8, k = i & 255;
    int orig = (r & 3) * 128 + (r >> 2);
    float v = (k < 128) ? Wih1[orig * 128 + k] : Whh1[orig * 128 + (k - 128)];
    Wcat1[i] = (_Float16)v;
  }
  if (i < 512) {
    int orig = (i & 3) * 128 + (i >> 2);
    bias0[i] = bih0[orig] + bhh0[orig];
    bias1[i] = bih1[orig] + bhh1[orig];
  }
}

// ------------------------------------------------------------- layer 0 ----
// 256 blocks x 512 threads, 2 chains/block.
// Input projection W_ih*x(+bias) batched 8 steps (16 MFMA cols, full util)
// into LDS double buffer; recurrent MFMA only K=128 (W_hh*h).
__global__ __launch_bounds__(512, 2) void lstm_l0(
    const float*    __restrict__ x,     // [B][T][64] fp32
    const _Float16* __restrict__ Wcat,  // [512][192] interleaved rows
    const float*    __restrict__ bias,  // [512] interleaved
    _Float16*       __restrict__ hs0) { // [B][T][128]
  __shared__ __align__(16) _Float16 xring[32][2][64];    // 8 KiB
  __shared__ __align__(16) _Float16 hist[32][2][HID];    // 16 KiB
  __shared__ __align__(16) _Float16 hsec[2][HID];        // 512 B
  __shared__ __align__(16) float    gbuf[2][512];        // [ch][u*4+g]
  __shared__ __align__(16) float    proj[2][8][2][512];  // 64 KiB [db][s][ch][row]
  const int tid  = threadIdx.x;
  const int lane = tid & 63;
  const int wv   = tid >> 6;
  const int m    = lane & 15;
  const int q    = lane >> 4;
  const int ch   = m & 1;
  const int b0   = blockIdx.x * 2;

  v8hf aih[4][2], ahh[4][4];
  #pragma unroll
  for (int i = 0; i < 4; ++i) {
    const int rt = wv * 4 + i;
    #pragma unroll
    for (int kt = 0; kt < 2; ++kt)
      aih[i][kt] = *(const v8hf*)&Wcat[(rt * 16 + m) * 192 + kt * 32 + q * 8];
    #pragma unroll
    for (int kt = 0; kt < 4; ++kt)
      ahh[i][kt] = *(const v8hf*)&Wcat[(rt * 16 + m) * 192 + 64 + kt * 32 + q * 8];
  }
  v4f cb[4];                           // bias (C layout), burst C-init
  #pragma unroll
  for (int i = 0; i < 4; ++i) {
    float4 b4 = *(const float4*)&bias[(wv * 4 + i) * 16 + q * 4];
    cb[i][0] = b4.x; cb[i][1] = b4.y; cb[i][2] = b4.z; cb[i][3] = b4.w;
  }

  const int sc = tid >> 7, sd = tid & 127;
  if (tid < 256) hsec[sc][sd] = (_Float16)0.0f;

  {  // ring fill steps 0..31: 512 items = 32 x 2ch x 8 segs
    const int s = tid >> 4, c = (tid >> 3) & 1, seg = tid & 7;
    const float* src = &x[((size_t)(b0 + c) * T_STEPS + s) * 64 + seg * 8];
    float4 a = *(const float4*)src;
    float4 b = *(const float4*)(src + 4);
    v8hf o;
    o[0] = (_Float16)a.x; o[1] = (_Float16)a.y; o[2] = (_Float16)a.z; o[3] = (_Float16)a.w;
    o[4] = (_Float16)b.x; o[5] = (_Float16)b.y; o[6] = (_Float16)b.z; o[7] = (_Float16)b.w;
    *(v8hf*)&xring[s][c][seg * 8] = o;
  }
  __syncthreads();

  #pragma unroll
  for (int pb = 0; pb < 2; ++pb) {     // pre-bursts: steps 0..7 -> db0, 8..15 -> db1
    const int t0 = pb * 8, s = m >> 1;
    v4f acc[4];
    #pragma unroll
    for (int i = 0; i < 4; ++i) acc[i] = cb[i];
    #pragma unroll
    for (int kt = 0; kt < 2; ++kt) {
      v8hf bfr = *(const v8hf*)&xring[(t0 + s) & 31][ch][kt * 32 + q * 8];
      #pragma unroll
      for (int i = 0; i < 4; ++i)
        acc[i] = __builtin_amdgcn_mfma_f32_16x16x32_f16(aih[i][kt], bfr, acc[i], 0, 0, 0);
    }
    #pragma unroll
    for (int i = 0; i < 4; ++i)
      *(v4f*)&proj[pb][s][ch][(wv * 4 + i) * 16 + q * 4] = acc[i];
  }
  __syncthreads();

  float c_state = 0.0f;

  for (int t = 0; t < T_STEPS; ++t) {
    // ---- phase A ----
    const bool refill = ((t & 15) == 0) && (t >= 16) && (t + 16 < T_STEPS) &&
                        (tid >= 256);
    float4 ra, rb; int rs = 0, rc = 0, rseg = 0;
    if (refill) {                      // x steps t+16..t+31: 256 items
      const int it = tid - 256;
      rs = t + 16 + (it >> 4); rc = (it >> 3) & 1; rseg = it & 7;
      const float* src = &x[((size_t)(b0 + rc) * T_STEPS + rs) * 64 + rseg * 8];
      ra = *(const float4*)src;
      rb = *(const float4*)(src + 4);
    }
    if (((t & 15) == 8) && (t >= 24)) {  // flush h steps t-24..t-9
      const int fs = (t - 24) + (tid >> 5), fc = (tid >> 4) & 1, fseg = tid & 15;
      *(v8hf*)&hs0[((size_t)(b0 + fc) * T_STEPS + fs) * HID + fseg * 8] =
          *(const v8hf*)&hist[fs & 31][fc][fseg * 8];
    }
    {  // recurrent MFMA: acc <- proj(t), += W_hh * h(t-1)
      const int db = (t >> 3) & 1, s = t & 7;
      v4f acc[4];
      #pragma unroll
      for (int i = 0; i < 4; ++i)
        acc[i] = *(const v4f*)&proj[db][s][ch][(wv * 4 + i) * 16 + q * 4];
      #pragma unroll
      for (int kt = 0; kt < 4; ++kt) {
        v8hf bfr = *(const v8hf*)&hsec[ch][kt * 32 + q * 8];
        #pragma unroll
        for (int i = 0; i < 4; ++i)
          acc[i] = __builtin_amdgcn_mfma_f32_16x16x32_f16(ahh[i][kt], bfr, acc[i], 0, 0, 0);
      }
      if (m < 2) {
        #pragma unroll
        for (int i = 0; i < 4; ++i)
          *(v4f*)&gbuf[ch][(wv * 16 + i * 4 + q) * 4] = acc[i];  // all 4 gates of u
      }
    }
    if (((t & 7) == 0) && (t >= 8) && (t + 8 < T_STEPS)) {  // burst proj t+8..t+15
      const int db = ((t >> 3) + 1) & 1, t0 = t + 8, s = m >> 1;
      v4f acc[4];
      #pragma unroll
      for (int i = 0; i < 4; ++i) acc[i] = cb[i];
      #pragma unroll
      for (int kt = 0; kt < 2; ++kt) {
        v8hf bfr = *(const v8hf*)&xring[(t0 + s) & 31][ch][kt * 32 + q * 8];
        #pragma unroll
        for (int i = 0; i < 4; ++i)
          acc[i] = __builtin_amdgcn_mfma_f32_16x16x32_f16(aih[i][kt], bfr, acc[i], 0, 0, 0);
      }
      #pragma unroll
      for (int i = 0; i < 4; ++i)
        *(v4f*)&proj[db][s][ch][(wv * 4 + i) * 16 + q * 4] = acc[i];
    }
    __syncthreads();

    // ---- phase B: act | ring write ----
    if (tid < 256) {
      float4 g4 = *(const float4*)&gbuf[sc][sd * 4];  // i,f,g,o of hidden sd
      c_state = sigm(g4.y) * c_state + sigm(g4.x) * tanh_f(g4.z);
      const float hval = sigm(g4.w) * tanh_f(c_state);
      const _Float16 hh = (_Float16)hval;
      hsec[sc][sd] = hh;
      hist[t & 31][sc][sd] = hh;
    } else if (refill) {
      v8hf o;
      o[0] = (_Float16)ra.x; o[1] = (_Float16)ra.y; o[2] = (_Float16)ra.z; o[3] = (_Float16)ra.w;
      o[4] = (_Float16)rb.x; o[5] = (_Float16)rb.y; o[6] = (_Float16)rb.z; o[7] = (_Float16)rb.w;
      *(v8hf*)&xring[rs & 31][rc][rseg * 8] = o;
    }
    __syncthreads();
  }
  {  // final flush: steps 496..511
    const int fs = 496 + (tid >> 5), fc = (tid >> 4) & 1, fseg = tid & 15;
    *(v8hf*)&hs0[((size_t)(b0 + fc) * T_STEPS + fs) * HID + fseg * 8] =
        *(const v8hf*)&hist[fs & 31][fc][fseg * 8];
  }
}

// ------------------------------------------------------------- layer 1 ----
// Same scheme; input projection is W_ih1 * h0 (K=128) from the h0 ring.
__global__ __launch_bounds__(512, 2) void lstm_l1(
    const _Float16* __restrict__ hs0,   // [B][T][128]
    const _Float16* __restrict__ Wcat,  // [512][256] interleaved rows
    const float*    __restrict__ bias,  // [512] interleaved
    float*          __restrict__ h2last) { // [B][128] fp32
  __shared__ __align__(16) _Float16 h0ring[32][2][HID];  // 16 KiB
  __shared__ __align__(16) _Float16 h1sec[2][HID];
  __shared__ __align__(16) float    gbuf[2][512];
  __shared__ __align__(16) float    proj[2][8][2][512];  // 64 KiB
  const int tid  = threadIdx.x;
  const int lane = tid & 63;
  const int wv   = tid >> 6;
  const int m    = lane & 15;
  const int q    = lane >> 4;
  const int ch   = m & 1;
  const int b0   = blockIdx.x * 2;

  v8hf aih[4][4], ahh[4][4];
  #pragma unroll
  for (int i = 0; i < 4; ++i) {
    const int rt = wv * 4 + i;
    #pragma unroll
    for (int kt = 0; kt < 4; ++kt) {
      aih[i][kt] = *(const v8hf*)&Wcat[(rt * 16 + m) * 256 + kt * 32 + q * 8];
      ahh[i][kt] = *(const v8hf*)&Wcat[(rt * 16 + m) * 256 + 128 + kt * 32 + q * 8];
    }
  }
  v4f cb[4];
  #pragma unroll
  for (int i = 0; i < 4; ++i) {
    float4 b4 = *(const float4*)&bias[(wv * 4 + i) * 16 + q * 4];
    cb[i][0] = b4.x; cb[i][1] = b4.y; cb[i][2] = b4.z; cb[i][3] = b4.w;
  }

  const int sc = tid >> 7, sd = tid & 127;
  if (tid < 256) h1sec[sc][sd] = (_Float16)0.0f;

  {  // ring fill steps 0..31: 1024 items
    #pragma unroll
    for (int r = 0; r < 2; ++r) {
      const int it = tid + r * 512;
      const int s = it >> 5, c = (it >> 4) & 1, seg = it & 15;
      *(v8hf*)&h0ring[s][c][seg * 8] =
          *(const v8hf*)&hs0[((size_t)(b0 + c) * T_STEPS + s) * HID + seg * 8];
    }
  }
  __syncthreads();

  #pragma unroll
  for (int pb = 0; pb < 2; ++pb) {     // pre-bursts
    const int t0 = pb * 8, s = m >> 1;
    v4f acc[4];
    #pragma unroll
    for (int i = 0; i < 4; ++i) acc[i] = cb[i];
    #pragma unroll
    for (int kt = 0; kt < 4; ++kt) {
      v8hf bfr = *(const v8hf*)&h0ring[(t0 + s) & 31][ch][kt * 32 + q * 8];
      #pragma unroll
      for (int i = 0; i < 4; ++i)
        acc[i] = __builtin_amdgcn_mfma_f32_16x16x32_f16(aih[i][kt], bfr, acc[i], 0, 0, 0);
    }
    #pragma unroll
    for (int i = 0; i < 4; ++i)
      *(v4f*)&proj[pb][s][ch][(wv * 4 + i) * 16 + q * 4] = acc[i];
  }
  __syncthreads();

  float c_state = 0.0f;

  for (int t = 0; t < T_STEPS; ++t) {
    // ---- phase A ----
    const bool refill = ((t & 15) == 0) && (t >= 16) && (t + 16 < T_STEPS);
    v8hf rv; int rs = 0, rc = 0, rseg = 0;
    if (refill) {                      // h0 steps t+16..t+31: 512 items
      rs = t + 16 + (tid >> 5); rc = (tid >> 4) & 1; rseg = tid & 15;
      rv = *(const v8hf*)&hs0[((size_t)(b0 + rc) * T_STEPS + rs) * HID + rseg * 8];
    }
    {  // recurrent
      const int db = (t >> 3) & 1, s = t & 7;
      v4f acc[4];
      #pragma unroll
      for (int i = 0; i < 4; ++i)
        acc[i] = *(const v4f*)&proj[db][s][ch][(wv * 4 + i) * 16 + q * 4];
      #pragma unroll
      for (int kt = 0; kt < 4; ++kt) {
        v8hf bfr = *(const v8hf*)&h1sec[ch][kt * 32 + q * 8];
        #pragma unroll
        for (int i = 0; i < 4; ++i)
          acc[i] = __builtin_amdgcn_mfma_f32_16x16x32_f16(ahh[i][kt], bfr, acc[i], 0, 0, 0);
      }
      if (m < 2) {
        #pragma unroll
        for (int i = 0; i < 4; ++i)
          *(v4f*)&gbuf[ch][(wv * 16 + i * 4 + q) * 4] = acc[i];
      }
    }
    if (((t & 7) == 0) && (t >= 8) && (t + 8 < T_STEPS)) {  // burst proj
      const int db = ((t >> 3) + 1) & 1, t0 = t + 8, s = m >> 1;
      v4f acc[4];
      #pragma unroll
      for (int i = 0; i < 4; ++i) acc[i] = cb[i];
      #pragma unroll
      for (int kt = 0; kt < 4; ++kt) {
        v8hf bfr = *(const v8hf*)&h0ring[(t0 + s) & 31][ch][kt * 32 + q * 8];
        #pragma unroll
        for (int i = 0; i < 4; ++i)
          acc[i] = __builtin_amdgcn_mfma_f32_16x16x32_f16(aih[i][kt], bfr, acc[i], 0, 0, 0);
      }
      #pragma unroll
      for (int i = 0; i < 4; ++i)
        *(v4f*)&proj[db][s][ch][(wv * 4 + i) * 16 + q * 4] = acc[i];
    }
    __syncthreads();

    // ---- phase B ----
    if (tid < 256) {
      float4 g4 = *(const float4*)&gbuf[sc][sd * 4];
      c_state = sigm(g4.y) * c_state + sigm(g4.x) * tanh_f(g4.z);
      const float hval = sigm(g4.w) * tanh_f(c_state);
      h1sec[sc][sd] = (_Float16)hval;
      if (t == T_STEPS - 1) h2last[(size_t)(b0 + sc) * HID + sd] = hval;
    }
    if (refill) *(v8hf*)&h0ring[rs & 31][rc][rseg * 8] = rv;
    __syncthreads();
  }
}

// ------------------------------------------------------------- fc head ----
__global__ __launch_bounds__(128) void fc_head(
    const float* __restrict__ h2last, const float* __restrict__ fc1w,
    const float* __restrict__ fc1b, const float* __restrict__ fc2w,
    const float* __restrict__ fc2b, float* __restrict__ out) {
  __shared__ float hb[128];
  __shared__ float part[2];
  const int b = blockIdx.x, j = threadIdx.x;
  hb[j] = h2last[(size_t)b * HID + j];
  __syncthreads();
  const float* wr = fc1w + j * HID;
  float acc = 0.f;
  #pragma unroll 8
  for (int d = 0; d < HID; ++d) acc += wr[d] * hb[d];
  float v = fmaxf(acc + fc1b[j], 0.f) * fc2w[j];
  #pragma unroll
  for (int s = 32; s > 0; s >>= 1) v += __shfl_down(v, s);
  if ((j & 63) == 0) part[j >> 6] = v;
  __syncthreads();
  if (j == 0) out[b] = part[0] + part[1] + fc2b[0];
}

// -------------------------------------------------------------- launch ----
extern "C" void kernel_launch(void* const* d_in, const int* in_sizes, int n_in,
                              void* d_out, int out_size, void* d_ws, size_t ws_size,
                              hipStream_t stream) {
  const float* x    = (const float*)d_in[0];
  const float* Wih0 = (const float*)d_in[1];
  const float* Whh0 = (const float*)d_in[2];
  const float* bih0 = (const float*)d_in[3];
  const float* bhh0 = (const float*)d_in[4];
  const float* Wih1 = (const float*)d_in[5];
  const float* Whh1 = (const float*)d_in[6];
  const float* bih1 = (const float*)d_in[7];
  const float* bhh1 = (const float*)d_in[8];
  const float* fc1w = (const float*)d_in[9];
  const float* fc1b = (const float*)d_in[10];
  const float* fc2w = (const float*)d_in[11];
  const float* fc2b = (const float*)d_in[12];
  float* out = (float*)d_out;

  char* ws = (char*)d_ws;
  const size_t OFF_HS0 = 0;                    // 512*512*128*2 = 64 MiB
  const size_t OFF_WC0 = 67108864;             // 512*192*2
  const size_t OFF_WC1 = OFF_WC0 + 196608;     // 512*256*2
  const size_t OFF_B0  = OFF_WC1 + 262144;     // 512*4
  const size_t OFF_B1  = OFF_B0 + 2048;
  const size_t OFF_H2L = OFF_B1 + 2048;        // 512*128*4

  _Float16* hs0    = (_Float16*)(ws + OFF_HS0);
  _Float16* Wcat0  = (_Float16*)(ws + OFF_WC0);
  _Float16* Wcat1  = (_Float16*)(ws + OFF_WC1);
  float*    bias0  = (float*)(ws + OFF_B0);
  float*    bias1  = (float*)(ws + OFF_B1);
  float*    h2last = (float*)(ws + OFF_H2L);

  prep_w<<<512, 256, 0, stream>>>(Wih0, Whh0, bih0, bhh0, Wih1, Whh1, bih1, bhh1,
                                  Wcat0, Wcat1, bias0, bias1);
  lstm_l0<<<256, 512, 0, stream>>>(x, Wcat0, bias0, hs0);
  lstm_l1<<<256, 512, 0, stream>>>(hs0, Wcat1, bias1, h2last);
  fc_head<<<512, 128, 0, stream>>>(h2last, fc1w, fc1b, fc2w, fc2b, out);
}

// Round 9
// 893.495 us; speedup vs baseline: 1.2015x; 1.2015x over previous
//
#include <hip/hip_runtime.h>

#define T_STEPS 512
#define HID     128

typedef _Float16 v8hf __attribute__((ext_vector_type(8)));
typedef float v4f __attribute__((ext_vector_type(4)));

__device__ __forceinline__ float rcpf(float x) {
#if __has_builtin(__builtin_amdgcn_rcpf)
  return __builtin_amdgcn_rcpf(x);
#else
  return 1.0f / x;
#endif
}
__device__ __forceinline__ float sigm(float x)  { return rcpf(1.0f + __expf(-x)); }
__device__ __forceinline__ float tanh_f(float x){ return 1.0f - 2.0f * rcpf(__expf(2.0f * x) + 1.0f); }

// ---------------------------------------------------------------- prep ----
// Gate-interleaved rows: packed row r = 4*u + g  <->  orig row g*128 + u.
__global__ __launch_bounds__(256) void prep_w(
    const float* __restrict__ Wih0, const float* __restrict__ Whh0,
    const float* __restrict__ bih0, const float* __restrict__ bhh0,
    const float* __restrict__ Wih1, const float* __restrict__ Whh1,
    const float* __restrict__ bih1, const float* __restrict__ bhh1,
    _Float16* __restrict__ Wcat0, _Float16* __restrict__ Wcat1,
    float* __restrict__ bias0, float* __restrict__ bias1) {
  int i = blockIdx.x * blockDim.x + threadIdx.x;
  if (i < 512 * 192) {                  // Wcat0 row r: [Wih0(64) | Whh0(128)]
    int r = i / 192, k = i - r * 192;
    int orig = (r & 3) * 128 + (r >> 2);
    float v = (k < 64) ? Wih0[orig * 64 + k] : Whh0[orig * 128 + (k - 64)];
    Wcat0[i] = (_Float16)v;
  }
  if (i < 512 * 256) {                  // Wcat1 row r: [Wih1(128) | Whh1(128)]
    int r = i >> 8, k = i & 255;
    int orig = (r & 3) * 128 + (r >> 2);
    float v = (k < 128) ? Wih1[orig * 128 + k] : Whh1[orig * 128 + (k - 128)];
    Wcat1[i] = (_Float16)v;
  }
  if (i < 512) {
    int orig = (i & 3) * 128 + (i >> 2);
    bias0[i] = bih0[orig] + bhh0[orig];
    bias1[i] = bih1[orig] + bhh1[orig];
  }
}

// ------------------------------------------------------------- layer 0 ----
// 256 blocks x 512 threads, 2 chains/block.
// Batched input projection kept in REGISTERS (psave): burst MFMA output col
// 2s+ch holds proj(step base+s); per-step recurrent MFMA uses psave as
// C-init with h broadcast to all cols; true gates appear at cols {2s,2s+1}.
__global__ __launch_bounds__(512, 2) void lstm_l0(
    const float*    __restrict__ x,     // [B][T][64] fp32
    const _Float16* __restrict__ Wcat,  // [512][192] interleaved rows
    const float*    __restrict__ bias,  // [512] interleaved
    _Float16*       __restrict__ hs0) { // [B][T][128]
  __shared__ __align__(16) _Float16 xring[32][2][72];    // padded rows
  __shared__ __align__(16) _Float16 hist[32][2][HID];
  __shared__ __align__(16) _Float16 hsec[2][HID];
  __shared__ __align__(16) float    gbuf[2][512];        // [ch][u*4+g]
  const int tid  = threadIdx.x;
  const int lane = tid & 63;
  const int wv   = tid >> 6;
  const int m    = lane & 15;
  const int q    = lane >> 4;
  const int ch   = m & 1;
  const int sb   = m >> 1;            // step-slot this col carries in bursts
  const int b0   = blockIdx.x * 2;

  v8hf aih[4][2], ahh[4][4];
  #pragma unroll
  for (int i = 0; i < 4; ++i) {
    const int rt = wv * 4 + i;
    #pragma unroll
    for (int kt = 0; kt < 2; ++kt)
      aih[i][kt] = *(const v8hf*)&Wcat[(rt * 16 + m) * 192 + kt * 32 + q * 8];
    #pragma unroll
    for (int kt = 0; kt < 4; ++kt)
      ahh[i][kt] = *(const v8hf*)&Wcat[(rt * 16 + m) * 192 + 64 + kt * 32 + q * 8];
  }
  v4f cb[4];
  #pragma unroll
  for (int i = 0; i < 4; ++i) {
    float4 b4 = *(const float4*)&bias[(wv * 4 + i) * 16 + q * 4];
    cb[i][0] = b4.x; cb[i][1] = b4.y; cb[i][2] = b4.z; cb[i][3] = b4.w;
  }

  const int sc = tid >> 7, sd = tid & 127;
  if (tid < 256) hsec[sc][sd] = (_Float16)0.0f;

  {  // ring fill steps 0..31: 512 items = 32 x 2ch x 8 segs
    const int s = tid >> 4, c = (tid >> 3) & 1, seg = tid & 7;
    const float* src = &x[((size_t)(b0 + c) * T_STEPS + s) * 64 + seg * 8];
    float4 a = *(const float4*)src;
    float4 b = *(const float4*)(src + 4);
    v8hf o;
    o[0] = (_Float16)a.x; o[1] = (_Float16)a.y; o[2] = (_Float16)a.z; o[3] = (_Float16)a.w;
    o[4] = (_Float16)b.x; o[5] = (_Float16)b.y; o[6] = (_Float16)b.z; o[7] = (_Float16)b.w;
    *(v8hf*)&xring[s][c][seg * 8] = o;
  }
  __syncthreads();

  v4f psave[4];
  {  // pre-burst: proj for steps 0..7 (this col: step sb)
    v4f a2[4];
    #pragma unroll
    for (int i = 0; i < 4; ++i) a2[i] = cb[i];
    #pragma unroll
    for (int kt = 0; kt < 2; ++kt) {
      v8hf bfr = *(const v8hf*)&xring[sb][ch][kt * 32 + q * 8];
      #pragma unroll
      for (int i = 0; i < 4; ++i)
        a2[i] = __builtin_amdgcn_mfma_f32_16x16x32_f16(aih[i][kt], bfr, a2[i], 0, 0, 0);
    }
    #pragma unroll
    for (int i = 0; i < 4; ++i) psave[i] = a2[i];
  }

  float c_state = 0.0f;

  for (int t = 0; t < T_STEPS; ++t) {
    // ---- phase A ----
    const bool refill = ((t & 15) == 0) && (t >= 16) && (t + 16 < T_STEPS) &&
                        (tid >= 256);
    float4 ra, rb; int rs = 0, rc = 0, rseg = 0;
    if (refill) {                      // x steps t+16..t+31: 256 items
      const int it = tid - 256;
      rs = t + 16 + (it >> 4); rc = (it >> 3) & 1; rseg = it & 7;
      const float* src = &x[((size_t)(b0 + rc) * T_STEPS + rs) * 64 + rseg * 8];
      ra = *(const float4*)src;
      rb = *(const float4*)(src + 4);
    }
    if (((t & 15) == 8) && (t >= 24)) {  // flush h steps t-24..t-9
      const int fs = (t - 24) + (tid >> 5), fc = (tid >> 4) & 1, fseg = tid & 15;
      *(v8hf*)&hs0[((size_t)(b0 + fc) * T_STEPS + fs) * HID + fseg * 8] =
          *(const v8hf*)&hist[fs & 31][fc][fseg * 8];
    }
    {  // recurrent MFMA: C-init = psave (this col's step), B = h(t-1) bcast
      v4f acc[4];
      #pragma unroll
      for (int kt = 0; kt < 4; ++kt) {
        v8hf bfr = *(const v8hf*)&hsec[ch][kt * 32 + q * 8];
        #pragma unroll
        for (int i = 0; i < 4; ++i)
          acc[i] = __builtin_amdgcn_mfma_f32_16x16x32_f16(
              ahh[i][kt], bfr, (kt == 0) ? psave[i] : acc[i], 0, 0, 0);
      }
      if (sb == (t & 7)) {             // this col pair holds step t's gates
        #pragma unroll
        for (int i = 0; i < 4; ++i)
          *(v4f*)&gbuf[ch][(wv * 16 + i * 4 + q) * 4] = acc[i];
      }
    }
    if (((t & 7) == 7) && (t + 1 < T_STEPS)) {  // burst proj for t+1..t+8
      const int slot = (t + 1 + sb) & 31;
      v4f a2[4];
      #pragma unroll
      for (int i = 0; i < 4; ++i) a2[i] = cb[i];
      #pragma unroll
      for (int kt = 0; kt < 2; ++kt) {
        v8hf bfr = *(const v8hf*)&xring[slot][ch][kt * 32 + q * 8];
        #pragma unroll
        for (int i = 0; i < 4; ++i)
          a2[i] = __builtin_amdgcn_mfma_f32_16x16x32_f16(aih[i][kt], bfr, a2[i], 0, 0, 0);
      }
      #pragma unroll
      for (int i = 0; i < 4; ++i) psave[i] = a2[i];
    }
    __syncthreads();

    // ---- phase B: act | ring write ----
    if (tid < 256) {
      float4 g4 = *(const float4*)&gbuf[sc][sd * 4];  // i,f,g,o of hidden sd
      c_state = sigm(g4.y) * c_state + sigm(g4.x) * tanh_f(g4.z);
      const float hval = sigm(g4.w) * tanh_f(c_state);
      const _Float16 hh = (_Float16)hval;
      hsec[sc][sd] = hh;
      hist[t & 31][sc][sd] = hh;
    } else if (refill) {
      v8hf o;
      o[0] = (_Float16)ra.x; o[1] = (_Float16)ra.y; o[2] = (_Float16)ra.z; o[3] = (_Float16)ra.w;
      o[4] = (_Float16)rb.x; o[5] = (_Float16)rb.y; o[6] = (_Float16)rb.z; o[7] = (_Float16)rb.w;
      *(v8hf*)&xring[rs & 31][rc][rseg * 8] = o;
    }
    __syncthreads();
  }
  {  // final flush: steps 496..511
    const int fs = 496 + (tid >> 5), fc = (tid >> 4) & 1, fseg = tid & 15;
    *(v8hf*)&hs0[((size_t)(b0 + fc) * T_STEPS + fs) * HID + fseg * 8] =
        *(const v8hf*)&hist[fs & 31][fc][fseg * 8];
  }
}

// ------------------------------------------------------------- layer 1 ----
// Same scheme; projection input is h0 (K=128) from the padded h0 ring.
__global__ __launch_bounds__(512, 2) void lstm_l1(
    const _Float16* __restrict__ hs0,   // [B][T][128]
    const _Float16* __restrict__ Wcat,  // [512][256] interleaved rows
    const float*    __restrict__ bias,  // [512] interleaved
    float*          __restrict__ h2last) { // [B][128] fp32
  __shared__ __align__(16) _Float16 h0ring[32][2][136];  // padded rows
  __shared__ __align__(16) _Float16 h1sec[2][HID];
  __shared__ __align__(16) float    gbuf[2][512];
  const int tid  = threadIdx.x;
  const int lane = tid & 63;
  const int wv   = tid >> 6;
  const int m    = lane & 15;
  const int q    = lane >> 4;
  const int ch   = m & 1;
  const int sb   = m >> 1;
  const int b0   = blockIdx.x * 2;

  v8hf aih[4][4], ahh[4][4];
  #pragma unroll
  for (int i = 0; i < 4; ++i) {
    const int rt = wv * 4 + i;
    #pragma unroll
    for (int kt = 0; kt < 4; ++kt) {
      aih[i][kt] = *(const v8hf*)&Wcat[(rt * 16 + m) * 256 + kt * 32 + q * 8];
      ahh[i][kt] = *(const v8hf*)&Wcat[(rt * 16 + m) * 256 + 128 + kt * 32 + q * 8];
    }
  }
  v4f cb[4];
  #pragma unroll
  for (int i = 0; i < 4; ++i) {
    float4 b4 = *(const float4*)&bias[(wv * 4 + i) * 16 + q * 4];
    cb[i][0] = b4.x; cb[i][1] = b4.y; cb[i][2] = b4.z; cb[i][3] = b4.w;
  }

  const int sc = tid >> 7, sd = tid & 127;
  if (tid < 256) h1sec[sc][sd] = (_Float16)0.0f;

  {  // ring fill steps 0..31: 1024 items
    #pragma unroll
    for (int r = 0; r < 2; ++r) {
      const int it = tid + r * 512;
      const int s = it >> 5, c = (it >> 4) & 1, seg = it & 15;
      *(v8hf*)&h0ring[s][c][seg * 8] =
          *(const v8hf*)&hs0[((size_t)(b0 + c) * T_STEPS + s) * HID + seg * 8];
    }
  }
  __syncthreads();

  v4f psave[4];
  {  // pre-burst: proj for steps 0..7
    v4f a2[4];
    #pragma unroll
    for (int i = 0; i < 4; ++i) a2[i] = cb[i];
    #pragma unroll
    for (int kt = 0; kt < 4; ++kt) {
      v8hf bfr = *(const v8hf*)&h0ring[sb][ch][kt * 32 + q * 8];
      #pragma unroll
      for (int i = 0; i < 4; ++i)
        a2[i] = __builtin_amdgcn_mfma_f32_16x16x32_f16(aih[i][kt], bfr, a2[i], 0, 0, 0);
    }
    #pragma unroll
    for (int i = 0; i < 4; ++i) psave[i] = a2[i];
  }

  float c_state = 0.0f;

  for (int t = 0; t < T_STEPS; ++t) {
    // ---- phase A ----
    const bool refill = ((t & 15) == 0) && (t >= 16) && (t + 16 < T_STEPS);
    v8hf rv; int rs = 0, rc = 0, rseg = 0;
    if (refill) {                      // h0 steps t+16..t+31: 512 items
      rs = t + 16 + (tid >> 5); rc = (tid >> 4) & 1; rseg = tid & 15;
      rv = *(const v8hf*)&hs0[((size_t)(b0 + rc) * T_STEPS + rs) * HID + rseg * 8];
    }
    {  // recurrent
      v4f acc[4];
      #pragma unroll
      for (int kt = 0; kt < 4; ++kt) {
        v8hf bfr = *(const v8hf*)&h1sec[ch][kt * 32 + q * 8];
        #pragma unroll
        for (int i = 0; i < 4; ++i)
          acc[i] = __builtin_amdgcn_mfma_f32_16x16x32_f16(
              ahh[i][kt], bfr, (kt == 0) ? psave[i] : acc[i], 0, 0, 0);
      }
      if (sb == (t & 7)) {
        #pragma unroll
        for (int i = 0; i < 4; ++i)
          *(v4f*)&gbuf[ch][(wv * 16 + i * 4 + q) * 4] = acc[i];
      }
    }
    if (((t & 7) == 7) && (t + 1 < T_STEPS)) {  // burst proj for t+1..t+8
      const int slot = (t + 1 + sb) & 31;
      v4f a2[4];
      #pragma unroll
      for (int i = 0; i < 4; ++i) a2[i] = cb[i];
      #pragma unroll
      for (int kt = 0; kt < 4; ++kt) {
        v8hf bfr = *(const v8hf*)&h0ring[slot][ch][kt * 32 + q * 8];
        #pragma unroll
        for (int i = 0; i < 4; ++i)
          a2[i] = __builtin_amdgcn_mfma_f32_16x16x32_f16(aih[i][kt], bfr, a2[i], 0, 0, 0);
      }
      #pragma unroll
      for (int i = 0; i < 4; ++i) psave[i] = a2[i];
    }
    __syncthreads();

    // ---- phase B ----
    if (tid < 256) {
      float4 g4 = *(const float4*)&gbuf[sc][sd * 4];
      c_state = sigm(g4.y) * c_state + sigm(g4.x) * tanh_f(g4.z);
      const float hval = sigm(g4.w) * tanh_f(c_state);
      h1sec[sc][sd] = (_Float16)hval;
      if (t == T_STEPS - 1) h2last[(size_t)(b0 + sc) * HID + sd] = hval;
    }
    if (refill) *(v8hf*)&h0ring[rs & 31][rc][rseg * 8] = rv;
    __syncthreads();
  }
}

// ------------------------------------------------------------- fc head ----
__global__ __launch_bounds__(128) void fc_head(
    const float* __restrict__ h2last, const float* __restrict__ fc1w,
    const float* __restrict__ fc1b, const float* __restrict__ fc2w,
    const float* __restrict__ fc2b, float* __restrict__ out) {
  __shared__ float hb[128];
  __shared__ float part[2];
  const int b = blockIdx.x, j = threadIdx.x;
  hb[j] = h2last[(size_t)b * HID + j];
  __syncthreads();
  const float* wr = fc1w + j * HID;
  float acc = 0.f;
  #pragma unroll 8
  for (int d = 0; d < HID; ++d) acc += wr[d] * hb[d];
  float v = fmaxf(acc + fc1b[j], 0.f) * fc2w[j];
  #pragma unroll
  for (int s = 32; s > 0; s >>= 1) v += __shfl_down(v, s);
  if ((j & 63) == 0) part[j >> 6] = v;
  __syncthreads();
  if (j == 0) out[b] = part[0] + part[1] + fc2b[0];
}

// -------------------------------------------------------------- launch ----
extern "C" void kernel_launch(void* const* d_in, const int* in_sizes, int n_in,
                              void* d_out, int out_size, void* d_ws, size_t ws_size,
                              hipStream_t stream) {
  const float* x    = (const float*)d_in[0];
  const float* Wih0 = (const float*)d_in[1];
  const float* Whh0 = (const float*)d_in[2];
  const float* bih0 = (const float*)d_in[3];
  const float* bhh0 = (const float*)d_in[4];
  const float* Wih1 = (const float*)d_in[5];
  const float* Whh1 = (const float*)d_in[6];
  const float* bih1 = (const float*)d_in[7];
  const float* bhh1 = (const float*)d_in[8];
  const float* fc1w = (const float*)d_in[9];
  const float* fc1b = (const float*)d_in[10];
  const float* fc2w = (const float*)d_in[11];
  const float* fc2b = (const float*)d_in[12];
  float* out = (float*)d_out;

  char* ws = (char*)d_ws;
  const size_t OFF_HS0 = 0;                    // 512*512*128*2 = 64 MiB
  const size_t OFF_WC0 = 67108864;             // 512*192*2
  const size_t OFF_WC1 = OFF_WC0 + 196608;     // 512*256*2
  const size_t OFF_B0  = OFF_WC1 + 262144;     // 512*4
  const size_t OFF_B1  = OFF_B0 + 2048;
  const size_t OFF_H2L = OFF_B1 + 2048;        // 512*128*4

  _Float16* hs0    = (_Float16*)(ws + OFF_HS0);
  _Float16* Wcat0  = (_Float16*)(ws + OFF_WC0);
  _Float16* Wcat1  = (_Float16*)(ws + OFF_WC1);
  float*    bias0  = (float*)(ws + OFF_B0);
  float*    bias1  = (float*)(ws + OFF_B1);
  float*    h2last = (float*)(ws + OFF_H2L);

  prep_w<<<512, 256, 0, stream>>>(Wih0, Whh0, bih0, bhh0, Wih1, Whh1, bih1, bhh1,
                                  Wcat0, Wcat1, bias0, bias1);
  lstm_l0<<<256, 512, 0, stream>>>(x, Wcat0, bias0, hs0);
  lstm_l1<<<256, 512, 0, stream>>>(hs0, Wcat1, bias1, h2last);
  fc_head<<<512, 128, 0, stream>>>(h2last, fc1w, fc1b, fc2w, fc2b, out);
}

// Round 10
// 891.713 us; speedup vs baseline: 1.2039x; 1.0020x over previous
//
#include <hip/hip_runtime.h>

#define T_STEPS 512
#define HID     128
#define GSTR    20   // gbuf row stride in floats (16B-aligned, bank-uniform)

typedef _Float16 v8hf __attribute__((ext_vector_type(8)));
typedef float v4f __attribute__((ext_vector_type(4)));

__device__ __forceinline__ float rcpf(float x) {
#if __has_builtin(__builtin_amdgcn_rcpf)
  return __builtin_amdgcn_rcpf(x);
#else
  return 1.0f / x;
#endif
}
__device__ __forceinline__ float sigm(float x)  { return rcpf(1.0f + __expf(-x)); }
__device__ __forceinline__ float tanh_f(float x){ return 1.0f - 2.0f * rcpf(__expf(2.0f * x) + 1.0f); }

// ---------------------------------------------------------------- prep ----
// Gate-interleaved rows: packed row r = 4*u + g  <->  orig row g*128 + u.
__global__ __launch_bounds__(256) void prep_w(
    const float* __restrict__ Wih0, const float* __restrict__ Whh0,
    const float* __restrict__ bih0, const float* __restrict__ bhh0,
    const float* __restrict__ Wih1, const float* __restrict__ Whh1,
    const float* __restrict__ bih1, const float* __restrict__ bhh1,
    _Float16* __restrict__ Wcat0, _Float16* __restrict__ Wcat1,
    float* __restrict__ bias0, float* __restrict__ bias1) {
  int i = blockIdx.x * blockDim.x + threadIdx.x;
  if (i < 512 * 192) {                  // Wcat0 row r: [Wih0(64) | Whh0(128)]
    int r = i / 192, k = i - r * 192;
    int orig = (r & 3) * 128 + (r >> 2);
    float v = (k < 64) ? Wih0[orig * 64 + k] : Whh0[orig * 128 + (k - 64)];
    Wcat0[i] = (_Float16)v;
  }
  if (i < 512 * 256) {                  // Wcat1 row r: [Wih1(128) | Whh1(128)]
    int r = i >> 8, k = i & 255;
    int orig = (r & 3) * 128 + (r >> 2);
    float v = (k < 128) ? Wih1[orig * 128 + k] : Whh1[orig * 128 + (k - 128)];
    Wcat1[i] = (_Float16)v;
  }
  if (i < 512) {
    int orig = (i & 3) * 128 + (i >> 2);
    bias0[i] = bih0[orig] + bhh0[orig];
    bias1[i] = bih1[orig] + bhh1[orig];
  }
}

// ------------------------------------------------------------- layer 0 ----
// 256 blocks x 512 threads, 2 chains/block. Batched input projection in
// registers (psave, col-pair 2s+ch = step base+s); recurrent MFMA K=128
// with psave as C-init; gates for step t at cols {2(t&7), 2(t&7)+1}.
// gbuf rows padded to GSTR floats -> bank-uniform float4 act reads.
__global__ __launch_bounds__(512, 2) void lstm_l0(
    const float*    __restrict__ x,     // [B][T][64] fp32
    const _Float16* __restrict__ Wcat,  // [512][192] interleaved rows
    const float*    __restrict__ bias,  // [512] interleaved
    _Float16*       __restrict__ hs0) { // [B][T][128]
  __shared__ __align__(16) _Float16 xring[32][2][72];    // padded rows
  __shared__ __align__(16) _Float16 hist[32][2][HID];
  __shared__ __align__(16) _Float16 hsec[2][HID];
  __shared__ __align__(16) float    gbuf[2][HID * GSTR]; // [ch][u*GSTR + g]
  const int tid  = threadIdx.x;
  const int lane = tid & 63;
  const int wv   = tid >> 6;
  const int m    = lane & 15;
  const int q    = lane >> 4;
  const int ch   = m & 1;
  const int sb   = m >> 1;            // step-slot this col carries in bursts
  const int b0   = blockIdx.x * 2;

  v8hf aih[4][2], ahh[4][4];
  #pragma unroll
  for (int i = 0; i < 4; ++i) {
    const int rt = wv * 4 + i;
    #pragma unroll
    for (int kt = 0; kt < 2; ++kt)
      aih[i][kt] = *(const v8hf*)&Wcat[(rt * 16 + m) * 192 + kt * 32 + q * 8];
    #pragma unroll
    for (int kt = 0; kt < 4; ++kt)
      ahh[i][kt] = *(const v8hf*)&Wcat[(rt * 16 + m) * 192 + 64 + kt * 32 + q * 8];
  }
  v4f cb[4];
  #pragma unroll
  for (int i = 0; i < 4; ++i) {
    float4 b4 = *(const float4*)&bias[(wv * 4 + i) * 16 + q * 4];
    cb[i][0] = b4.x; cb[i][1] = b4.y; cb[i][2] = b4.z; cb[i][3] = b4.w;
  }

  const int sc = tid >> 7, sd = tid & 127;
  if (tid < 256) hsec[sc][sd] = (_Float16)0.0f;

  {  // ring fill steps 0..31: 512 items = 32 x 2ch x 8 segs
    const int s = tid >> 4, c = (tid >> 3) & 1, seg = tid & 7;
    const float* src = &x[((size_t)(b0 + c) * T_STEPS + s) * 64 + seg * 8];
    float4 a = *(const float4*)src;
    float4 b = *(const float4*)(src + 4);
    v8hf o;
    o[0] = (_Float16)a.x; o[1] = (_Float16)a.y; o[2] = (_Float16)a.z; o[3] = (_Float16)a.w;
    o[4] = (_Float16)b.x; o[5] = (_Float16)b.y; o[6] = (_Float16)b.z; o[7] = (_Float16)b.w;
    *(v8hf*)&xring[s][c][seg * 8] = o;
  }
  __syncthreads();

  v4f psave[4];
  {  // pre-burst: proj for steps 0..7 (this col: step sb)
    v4f a2[4];
    #pragma unroll
    for (int i = 0; i < 4; ++i) a2[i] = cb[i];
    #pragma unroll
    for (int kt = 0; kt < 2; ++kt) {
      v8hf bfr = *(const v8hf*)&xring[sb][ch][kt * 32 + q * 8];
      #pragma unroll
      for (int i = 0; i < 4; ++i)
        a2[i] = __builtin_amdgcn_mfma_f32_16x16x32_f16(aih[i][kt], bfr, a2[i], 0, 0, 0);
    }
    #pragma unroll
    for (int i = 0; i < 4; ++i) psave[i] = a2[i];
  }

  float c_state = 0.0f;

  for (int t = 0; t < T_STEPS; ++t) {
    // ---- phase A ----
    const bool refill = ((t & 15) == 0) && (t >= 16) && (t + 16 < T_STEPS) &&
                        (tid >= 256);
    float4 ra, rb; int rs = 0, rc = 0, rseg = 0;
    if (refill) {                      // x steps t+16..t+31: 256 items
      const int it = tid - 256;
      rs = t + 16 + (it >> 4); rc = (it >> 3) & 1; rseg = it & 7;
      const float* src = &x[((size_t)(b0 + rc) * T_STEPS + rs) * 64 + rseg * 8];
      ra = *(const float4*)src;
      rb = *(const float4*)(src + 4);
    }
    if (((t & 15) == 8) && (t >= 24)) {  // flush h steps t-24..t-9
      const int fs = (t - 24) + (tid >> 5), fc = (tid >> 4) & 1, fseg = tid & 15;
      *(v8hf*)&hs0[((size_t)(b0 + fc) * T_STEPS + fs) * HID + fseg * 8] =
          *(const v8hf*)&hist[fs & 31][fc][fseg * 8];
    }
    {  // recurrent MFMA: C-init = psave (this col's step), B = h(t-1) bcast
      v4f acc[4];
      #pragma unroll
      for (int kt = 0; kt < 4; ++kt) {
        v8hf bfr = *(const v8hf*)&hsec[ch][kt * 32 + q * 8];
        #pragma unroll
        for (int i = 0; i < 4; ++i)
          acc[i] = __builtin_amdgcn_mfma_f32_16x16x32_f16(
              ahh[i][kt], bfr, (kt == 0) ? psave[i] : acc[i], 0, 0, 0);
      }
      if (sb == (t & 7)) {             // this col pair holds step t's gates
        #pragma unroll
        for (int i = 0; i < 4; ++i)
          *(v4f*)&gbuf[ch][(wv * 16 + i * 4 + q) * GSTR] = acc[i];
      }
    }
    if (((t & 7) == 7) && (t + 1 < T_STEPS)) {  // burst proj for t+1..t+8
      const int slot = (t + 1 + sb) & 31;
      v4f a2[4];
      #pragma unroll
      for (int i = 0; i < 4; ++i) a2[i] = cb[i];
      #pragma unroll
      for (int kt = 0; kt < 2; ++kt) {
        v8hf bfr = *(const v8hf*)&xring[slot][ch][kt * 32 + q * 8];
        #pragma unroll
        for (int i = 0; i < 4; ++i)
          a2[i] = __builtin_amdgcn_mfma_f32_16x16x32_f16(aih[i][kt], bfr, a2[i], 0, 0, 0);
      }
      #pragma unroll
      for (int i = 0; i < 4; ++i) psave[i] = a2[i];
    }
    __syncthreads();

    // ---- phase B: act | ring write ----
    if (tid < 256) {
      float4 g4 = *(const float4*)&gbuf[sc][sd * GSTR];  // i,f,g,o of unit sd
      c_state = sigm(g4.y) * c_state + sigm(g4.x) * tanh_f(g4.z);
      const float hval = sigm(g4.w) * tanh_f(c_state);
      const _Float16 hh = (_Float16)hval;
      hsec[sc][sd] = hh;
      hist[t & 31][sc][sd] = hh;
    } else if (refill) {
      v8hf o;
      o[0] = (_Float16)ra.x; o[1] = (_Float16)ra.y; o[2] = (_Float16)ra.z; o[3] = (_Float16)ra.w;
      o[4] = (_Float16)rb.x; o[5] = (_Float16)rb.y; o[6] = (_Float16)rb.z; o[7] = (_Float16)rb.w;
      *(v8hf*)&xring[rs & 31][rc][rseg * 8] = o;
    }
    __syncthreads();
  }
  {  // final flush: steps 496..511
    const int fs = 496 + (tid >> 5), fc = (tid >> 4) & 1, fseg = tid & 15;
    *(v8hf*)&hs0[((size_t)(b0 + fc) * T_STEPS + fs) * HID + fseg * 8] =
        *(const v8hf*)&hist[fs & 31][fc][fseg * 8];
  }
}

// ------------------------------------------------------------- layer 1 ----
// Same scheme; projection input is h0 (K=128) from the padded h0 ring.
// Refill loads carried by waves 4-7 only (act waves stay vmcnt-clean).
__global__ __launch_bounds__(512, 2) void lstm_l1(
    const _Float16* __restrict__ hs0,   // [B][T][128]
    const _Float16* __restrict__ Wcat,  // [512][256] interleaved rows
    const float*    __restrict__ bias,  // [512] interleaved
    float*          __restrict__ h2last) { // [B][128] fp32
  __shared__ __align__(16) _Float16 h0ring[32][2][136];  // padded rows
  __shared__ __align__(16) _Float16 h1sec[2][HID];
  __shared__ __align__(16) float    gbuf[2][HID * GSTR];
  const int tid  = threadIdx.x;
  const int lane = tid & 63;
  const int wv   = tid >> 6;
  const int m    = lane & 15;
  const int q    = lane >> 4;
  const int ch   = m & 1;
  const int sb   = m >> 1;
  const int b0   = blockIdx.x * 2;

  v8hf aih[4][4], ahh[4][4];
  #pragma unroll
  for (int i = 0; i < 4; ++i) {
    const int rt = wv * 4 + i;
    #pragma unroll
    for (int kt = 0; kt < 4; ++kt) {
      aih[i][kt] = *(const v8hf*)&Wcat[(rt * 16 + m) * 256 + kt * 32 + q * 8];
      ahh[i][kt] = *(const v8hf*)&Wcat[(rt * 16 + m) * 256 + 128 + kt * 32 + q * 8];
    }
  }
  v4f cb[4];
  #pragma unroll
  for (int i = 0; i < 4; ++i) {
    float4 b4 = *(const float4*)&bias[(wv * 4 + i) * 16 + q * 4];
    cb[i][0] = b4.x; cb[i][1] = b4.y; cb[i][2] = b4.z; cb[i][3] = b4.w;
  }

  const int sc = tid >> 7, sd = tid & 127;
  if (tid < 256) h1sec[sc][sd] = (_Float16)0.0f;

  {  // ring fill steps 0..31: 1024 items
    #pragma unroll
    for (int r = 0; r < 2; ++r) {
      const int it = tid + r * 512;
      const int s = it >> 5, c = (it >> 4) & 1, seg = it & 15;
      *(v8hf*)&h0ring[s][c][seg * 8] =
          *(const v8hf*)&hs0[((size_t)(b0 + c) * T_STEPS + s) * HID + seg * 8];
    }
  }
  __syncthreads();

  v4f psave[4];
  {  // pre-burst: proj for steps 0..7
    v4f a2[4];
    #pragma unroll
    for (int i = 0; i < 4; ++i) a2[i] = cb[i];
    #pragma unroll
    for (int kt = 0; kt < 4; ++kt) {
      v8hf bfr = *(const v8hf*)&h0ring[sb][ch][kt * 32 + q * 8];
      #pragma unroll
      for (int i = 0; i < 4; ++i)
        a2[i] = __builtin_amdgcn_mfma_f32_16x16x32_f16(aih[i][kt], bfr, a2[i], 0, 0, 0);
    }
    #pragma unroll
    for (int i = 0; i < 4; ++i) psave[i] = a2[i];
  }

  float c_state = 0.0f;

  for (int t = 0; t < T_STEPS; ++t) {
    // ---- phase A ----
    const bool refill = ((t & 15) == 0) && (t >= 16) && (t + 16 < T_STEPS) &&
                        (tid >= 256);
    v8hf rv0, rv1; int rs0 = 0, rc0 = 0, rg0 = 0, rs1 = 0, rc1 = 0, rg1 = 0;
    if (refill) {                      // h0 steps t+16..t+31: 512 items, 2/lane
      const int i0 = tid - 256, i1 = i0 + 256;
      rs0 = t + 16 + (i0 >> 5); rc0 = (i0 >> 4) & 1; rg0 = i0 & 15;
      rs1 = t + 16 + (i1 >> 5); rc1 = (i1 >> 4) & 1; rg1 = i1 & 15;
      rv0 = *(const v8hf*)&hs0[((size_t)(b0 + rc0) * T_STEPS + rs0) * HID + rg0 * 8];
      rv1 = *(const v8hf*)&hs0[((size_t)(b0 + rc1) * T_STEPS + rs1) * HID + rg1 * 8];
    }
    {  // recurrent
      v4f acc[4];
      #pragma unroll
      for (int kt = 0; kt < 4; ++kt) {
        v8hf bfr = *(const v8hf*)&h1sec[ch][kt * 32 + q * 8];
        #pragma unroll
        for (int i = 0; i < 4; ++i)
          acc[i] = __builtin_amdgcn_mfma_f32_16x16x32_f16(
              ahh[i][kt], bfr, (kt == 0) ? psave[i] : acc[i], 0, 0, 0);
      }
      if (sb == (t & 7)) {
        #pragma unroll
        for (int i = 0; i < 4; ++i)
          *(v4f*)&gbuf[ch][(wv * 16 + i * 4 + q) * GSTR] = acc[i];
      }
    }
    if (((t & 7) == 7) && (t + 1 < T_STEPS)) {  // burst proj for t+1..t+8
      const int slot = (t + 1 + sb) & 31;
      v4f a2[4];
      #pragma unroll
      for (int i = 0; i < 4; ++i) a2[i] = cb[i];
      #pragma unroll
      for (int kt = 0; kt < 4; ++kt) {
        v8hf bfr = *(const v8hf*)&h0ring[slot][ch][kt * 32 + q * 8];
        #pragma unroll
        for (int i = 0; i < 4; ++i)
          a2[i] = __builtin_amdgcn_mfma_f32_16x16x32_f16(aih[i][kt], bfr, a2[i], 0, 0, 0);
      }
      #pragma unroll
      for (int i = 0; i < 4; ++i) psave[i] = a2[i];
    }
    __syncthreads();

    // ---- phase B ----
    if (tid < 256) {
      float4 g4 = *(const float4*)&gbuf[sc][sd * GSTR];
      c_state = sigm(g4.y) * c_state + sigm(g4.x) * tanh_f(g4.z);
      const float hval = sigm(g4.w) * tanh_f(c_state);
      h1sec[sc][sd] = (_Float16)hval;
      if (t == T_STEPS - 1) h2last[(size_t)(b0 + sc) * HID + sd] = hval;
    } else if (refill) {
      *(v8hf*)&h0ring[rs0 & 31][rc0][rg0 * 8] = rv0;
      *(v8hf*)&h0ring[rs1 & 31][rc1][rg1 * 8] = rv1;
    }
    __syncthreads();
  }
}

// ------------------------------------------------------------- fc head ----
__global__ __launch_bounds__(128) void fc_head(
    const float* __restrict__ h2last, const float* __restrict__ fc1w,
    const float* __restrict__ fc1b, const float* __restrict__ fc2w,
    const float* __restrict__ fc2b, float* __restrict__ out) {
  __shared__ float hb[128];
  __shared__ float part[2];
  const int b = blockIdx.x, j = threadIdx.x;
  hb[j] = h2last[(size_t)b * HID + j];
  __syncthreads();
  const float* wr = fc1w + j * HID;
  float acc = 0.f;
  #pragma unroll 8
  for (int d = 0; d < HID; ++d) acc += wr[d] * hb[d];
  float v = fmaxf(acc + fc1b[j], 0.f) * fc2w[j];
  #pragma unroll
  for (int s = 32; s > 0; s >>= 1) v += __shfl_down(v, s);
  if ((j & 63) == 0) part[j >> 6] = v;
  __syncthreads();
  if (j == 0) out[b] = part[0] + part[1] + fc2b[0];
}

// -------------------------------------------------------------- launch ----
extern "C" void kernel_launch(void* const* d_in, const int* in_sizes, int n_in,
                              void* d_out, int out_size, void* d_ws, size_t ws_size,
                              hipStream_t stream) {
  const float* x    = (const float*)d_in[0];
  const float* Wih0 = (const float*)d_in[1];
  const float* Whh0 = (const float*)d_in[2];
  const float* bih0 = (const float*)d_in[3];
  const float* bhh0 = (const float*)d_in[4];
  const float* Wih1 = (const float*)d_in[5];
  const float* Whh1 = (const float*)d_in[6];
  const float* bih1 = (const float*)d_in[7];
  const float* bhh1 = (const float*)d_in[8];
  const float* fc1w = (const float*)d_in[9];
  const float* fc1b = (const float*)d_in[10];
  const float* fc2w = (const float*)d_in[11];
  const float* fc2b = (const float*)d_in[12];
  float* out = (float*)d_out;

  char* ws = (char*)d_ws;
  const size_t OFF_HS0 = 0;                    // 512*512*128*2 = 64 MiB
  const size_t OFF_WC0 = 67108864;             // 512*192*2
  const size_t OFF_WC1 = OFF_WC0 + 196608;     // 512*256*2
  const size_t OFF_B0  = OFF_WC1 + 262144;     // 512*4
  const size_t OFF_B1  = OFF_B0 + 2048;
  const size_t OFF_H2L = OFF_B1 + 2048;        // 512*128*4

  _Float16* hs0    = (_Float16*)(ws + OFF_HS0);
  _Float16* Wcat0  = (_Float16*)(ws + OFF_WC0);
  _Float16* Wcat1  = (_Float16*)(ws + OFF_WC1);
  float*    bias0  = (float*)(ws + OFF_B0);
  float*    bias1  = (float*)(ws + OFF_B1);
  float*    h2last = (float*)(ws + OFF_H2L);

  prep_w<<<512, 256, 0, stream>>>(Wih0, Whh0, bih0, bhh0, Wih1, Whh1, bih1, bhh1,
                                  Wcat0, Wcat1, bias0, bias1);
  lstm_l0<<<256, 512, 0, stream>>>(x, Wcat0, bias0, hs0);
  lstm_l1<<<256, 512, 0, stream>>>(hs0, Wcat1, bias1, h2last);
  fc_head<<<512, 128, 0, stream>>>(h2last, fc1w, fc1b, fc2w, fc2b, out);
}